// Round 1
// baseline (533.319 us; speedup 1.0000x reference)
//
#include <hip/hip_runtime.h>
#include <hip/hip_bf16.h>

// Orthogonal: out = X @ Q^T with Q = prod_{i=0..511} (I - 2 u_i u_i^T),
// u_i = rows of U (unnormalized). Reference applies the chain to X^T
// sequentially; the chain is column-independent, so we apply it to the
// columns of I (phase 1, fp32, 1 wave/column) and then do one GEMM
// (phase 2, bf16 hi/lo split, 3 MFMA terms, fp32 accumulate).

#define D 512
#define BATCHN 65536

typedef __bf16 bf16_t;
typedef __bf16 bf16x4 __attribute__((ext_vector_type(4)));
typedef __bf16 bf16x8 __attribute__((ext_vector_type(8)));
typedef float f32x4 __attribute__((ext_vector_type(4)));

// ---------------- Phase 1: compose Q ----------------
// One wave per column j of Q. Column starts as e_j, then for k=511..0:
//   c <- c - 2 u_k (u_k . c)      (same order as reference's scan over U[::-1])
// Lane l holds elements [8l, 8l+8). Writes Q split into bf16 hi/lo, row-major.
__global__ __launch_bounds__(256) void compose_q(const float* __restrict__ U,
                                                 bf16_t* __restrict__ Qh,
                                                 bf16_t* __restrict__ Ql) {
  const int lane = threadIdx.x & 63;
  const int wave = threadIdx.x >> 6;
  const int col = blockIdx.x * 4 + wave;  // 0..511
  const int base = lane * 8;

  float c[8];
#pragma unroll
  for (int r = 0; r < 8; ++r) c[r] = (base + r == col) ? 1.0f : 0.0f;

  for (int k = D - 1; k >= 0; --k) {
    const float4* up = reinterpret_cast<const float4*>(U + (size_t)k * D + base);
    float4 v0 = up[0];
    float4 v1 = up[1];
    float v[8] = {v0.x, v0.y, v0.z, v0.w, v1.x, v1.y, v1.z, v1.w};
    // tree-shaped lane-local dot to shorten the serial chain
    float d0 = v[0] * c[0] + v[1] * c[1];
    float d1 = v[2] * c[2] + v[3] * c[3];
    float d2 = v[4] * c[4] + v[5] * c[5];
    float d3 = v[6] * c[6] + v[7] * c[7];
    float dot = (d0 + d1) + (d2 + d3);
#pragma unroll
    for (int off = 32; off >= 1; off >>= 1) dot += __shfl_xor(dot, off, 64);
    float s = 2.0f * dot;
#pragma unroll
    for (int r = 0; r < 8; ++r) c[r] = fmaf(-s, v[r], c[r]);
  }

#pragma unroll
  for (int r = 0; r < 8; ++r) {
    float q = c[r];
    bf16_t hi = (bf16_t)q;
    float lo = q - (float)hi;
    Qh[(size_t)(base + r) * D + col] = hi;
    Ql[(size_t)(base + r) * D + col] = (bf16_t)lo;
  }
}

// ---------------- Phase 2: out = X @ Q^T ----------------
// C[b,i] = sum_k X[b,k] * Q[i,k].  Q row-major IS the B^T operand.
// bf16 split: X = Xh + Xl, Q = Qh + Ql; C ~= Xh*Qh + Xh*Ql + Xl*Qh.
#define BM 128
#define BN 128
#define BK 32
#define LDS_STRIDE 40  // bf16 elems: 80B rows -> <=2-way bank aliasing on ds_read_b128 (free)

__global__ __launch_bounds__(256) void gemm_xqt(const float* __restrict__ X,
                                                const bf16_t* __restrict__ Qh,
                                                const bf16_t* __restrict__ Ql,
                                                float* __restrict__ out) {
  __shared__ __align__(16) bf16_t Ah[BM * LDS_STRIDE];
  __shared__ __align__(16) bf16_t Al[BM * LDS_STRIDE];
  __shared__ __align__(16) bf16_t Bh[BN * LDS_STRIDE];
  __shared__ __align__(16) bf16_t Bl[BN * LDS_STRIDE];

  const int tid = threadIdx.x;
  const int lane = tid & 63;
  const int wave = tid >> 6;
  const int brow = (int)(blockIdx.x >> 2) * BM;  // M-tile origin
  const int bcol = (int)(blockIdx.x & 3) * BN;   // N-tile origin
  const int wr = wave >> 1;  // 0..1 (M half)
  const int wc = wave & 1;   // 0..1 (N half)

  const f32x4 zero = {0.f, 0.f, 0.f, 0.f};
  f32x4 acc[4][4];
#pragma unroll
  for (int m = 0; m < 4; ++m)
#pragma unroll
    for (int n = 0; n < 4; ++n) acc[m][n] = zero;

  // staging decomposition
  const int arow = tid >> 1;        // 0..127
  const int acol = (tid & 1) * 16;  // 0 or 16 (fp32 elems)
  const int b_r = tid >> 2;         // 0..63
  const int b_c = (tid & 3) * 8;    // 0,8,16,24 (bf16 elems)

  const int fr = lane & 15;        // fragment row/col
  const int fk = (lane >> 4) * 8;  // fragment k offset

  for (int k0 = 0; k0 < D; k0 += BK) {
    // ---- global loads into regs ----
    const float4* ag =
        reinterpret_cast<const float4*>(X + (size_t)(brow + arow) * D + k0 + acol);
    float4 af[4];
#pragma unroll
    for (int j = 0; j < 4; ++j) af[j] = ag[j];

    uint4 bh0 = *reinterpret_cast<const uint4*>(Qh + (size_t)(bcol + b_r) * D + k0 + b_c);
    uint4 bh1 = *reinterpret_cast<const uint4*>(Qh + (size_t)(bcol + 64 + b_r) * D + k0 + b_c);
    uint4 bl0 = *reinterpret_cast<const uint4*>(Ql + (size_t)(bcol + b_r) * D + k0 + b_c);
    uint4 bl1 = *reinterpret_cast<const uint4*>(Ql + (size_t)(bcol + 64 + b_r) * D + k0 + b_c);

    __syncthreads();  // previous iteration's LDS reads complete

    // ---- split A to bf16 hi/lo and write LDS ----
#pragma unroll
    for (int j = 0; j < 4; ++j) {
      float vals[4] = {af[j].x, af[j].y, af[j].z, af[j].w};
      bf16x4 hv, lv;
#pragma unroll
      for (int e = 0; e < 4; ++e) {
        float f = vals[e];
        bf16_t h = (bf16_t)f;
        hv[e] = h;
        lv[e] = (bf16_t)(f - (float)h);
      }
      const int idx = arow * LDS_STRIDE + acol + j * 4;
      *reinterpret_cast<bf16x4*>(&Ah[idx]) = hv;
      *reinterpret_cast<bf16x4*>(&Al[idx]) = lv;
    }
    // ---- write B tiles ----
    *reinterpret_cast<uint4*>(&Bh[b_r * LDS_STRIDE + b_c]) = bh0;
    *reinterpret_cast<uint4*>(&Bh[(b_r + 64) * LDS_STRIDE + b_c]) = bh1;
    *reinterpret_cast<uint4*>(&Bl[b_r * LDS_STRIDE + b_c]) = bl0;
    *reinterpret_cast<uint4*>(&Bl[(b_r + 64) * LDS_STRIDE + b_c]) = bl1;

    __syncthreads();

    // ---- fragments + MFMA ----
    bf16x8 a_h[4], a_l[4], b_h[4], b_l[4];
#pragma unroll
    for (int m = 0; m < 4; ++m) {
      const int row = wr * 64 + m * 16 + fr;
      a_h[m] = *reinterpret_cast<const bf16x8*>(&Ah[row * LDS_STRIDE + fk]);
      a_l[m] = *reinterpret_cast<const bf16x8*>(&Al[row * LDS_STRIDE + fk]);
    }
#pragma unroll
    for (int n = 0; n < 4; ++n) {
      const int colr = wc * 64 + n * 16 + fr;
      b_h[n] = *reinterpret_cast<const bf16x8*>(&Bh[colr * LDS_STRIDE + fk]);
      b_l[n] = *reinterpret_cast<const bf16x8*>(&Bl[colr * LDS_STRIDE + fk]);
    }
#pragma unroll
    for (int m = 0; m < 4; ++m)
#pragma unroll
      for (int n = 0; n < 4; ++n) {
        acc[m][n] = __builtin_amdgcn_mfma_f32_16x16x32_bf16(a_h[m], b_h[n], acc[m][n], 0, 0, 0);
        acc[m][n] = __builtin_amdgcn_mfma_f32_16x16x32_bf16(a_h[m], b_l[n], acc[m][n], 0, 0, 0);
        acc[m][n] = __builtin_amdgcn_mfma_f32_16x16x32_bf16(a_l[m], b_h[n], acc[m][n], 0, 0, 0);
      }
  }

  // ---- epilogue: C/D layout col=lane&15, row=(lane>>4)*4+j ----
  const int orow0 = brow + wr * 64;
  const int ocol0 = bcol + wc * 64;
  const int cr = (lane >> 4) * 4;
  const int cc = lane & 15;
#pragma unroll
  for (int m = 0; m < 4; ++m)
#pragma unroll
    for (int n = 0; n < 4; ++n)
#pragma unroll
      for (int j = 0; j < 4; ++j) {
        const int row = orow0 + m * 16 + cr + j;
        const int col = ocol0 + n * 16 + cc;
        out[(size_t)row * D + col] = acc[m][n][j];
      }
}

extern "C" void kernel_launch(void* const* d_in, const int* in_sizes, int n_in,
                              void* d_out, int out_size, void* d_ws, size_t ws_size,
                              hipStream_t stream) {
  const float* X = (const float*)d_in[0];
  const float* U = (const float*)d_in[1];
  float* out = (float*)d_out;

  bf16_t* Qh = (bf16_t*)d_ws;
  bf16_t* Ql = Qh + (size_t)D * D;  // 512 KiB each; ws usage = 1 MiB

  compose_q<<<D / 4, 256, 0, stream>>>(U, Qh, Ql);
  gemm_xqt<<<(BATCHN / BM) * (D / BN), 256, 0, stream>>>(X, Qh, Ql, out);
}

// Round 4
// 506.396 us; speedup vs baseline: 1.0532x; 1.0532x over previous
//
#include <hip/hip_runtime.h>
#include <hip/hip_bf16.h>

// Orthogonal: out = X @ Q^T with Q = prod_{i=0..511} (I - 2 u_i u_i^T).
// Phase 1: apply the reflector chain to columns of I (1 wave/column),
//          DPP-based wave reduction + 2-row register prefetch.
// Phase 2: GEMM out = X Q^T, bf16 hi/lo split (3 MFMA terms, fp32 acc),
//          double-buffered LDS, prefetch-across-raw-barrier (T4), XCD swizzle.

#define D 512
#define BATCHN 65536

typedef __bf16 bf16_t;
typedef __bf16 bf16x4 __attribute__((ext_vector_type(4)));
typedef __bf16 bf16x8 __attribute__((ext_vector_type(8)));
typedef float f32x4 __attribute__((ext_vector_type(4)));

// ---------------- Phase 1: compose Q ----------------
template <int CTRL, int ROWMASK>
__device__ __forceinline__ float dpp_add(float x) {
  int p = __builtin_amdgcn_update_dpp(0, __float_as_int(x), CTRL, ROWMASK, 0xf, true);
  return x + __int_as_float(p);
}

// Full-wave (64) sum; result broadcast to all lanes via readlane(63).
__device__ __forceinline__ float wave_sum64(float x) {
  x = dpp_add<0x111, 0xf>(x);  // row_shr:1
  x = dpp_add<0x112, 0xf>(x);  // row_shr:2
  x = dpp_add<0x114, 0xf>(x);  // row_shr:4
  x = dpp_add<0x118, 0xf>(x);  // row_shr:8  -> lane15 of each row has row sum
  x = dpp_add<0x142, 0xa>(x);  // row_bcast15 -> lane31: rows0-1, lane63: rows2-3
  x = dpp_add<0x143, 0xc>(x);  // row_bcast31 -> lane63: total
  return __int_as_float(__builtin_amdgcn_readlane(__float_as_int(x), 63));
}

__device__ __forceinline__ void hh_step(float c[8], const float4& v0, const float4& v1) {
  // balanced tree dot of the lane-local 8 elements
  float m0 = v0.x * c[0], m1 = v0.y * c[1], m2 = v0.z * c[2], m3 = v0.w * c[3];
  float m4 = v1.x * c[4], m5 = v1.y * c[5], m6 = v1.z * c[6], m7 = v1.w * c[7];
  float d0 = m0 + m1, d1 = m2 + m3, d2 = m4 + m5, d3 = m6 + m7;
  float dot = (d0 + d1) + (d2 + d3);
  float s = 2.0f * wave_sum64(dot);
  c[0] = fmaf(-s, v0.x, c[0]);
  c[1] = fmaf(-s, v0.y, c[1]);
  c[2] = fmaf(-s, v0.z, c[2]);
  c[3] = fmaf(-s, v0.w, c[3]);
  c[4] = fmaf(-s, v1.x, c[4]);
  c[5] = fmaf(-s, v1.y, c[5]);
  c[6] = fmaf(-s, v1.z, c[6]);
  c[7] = fmaf(-s, v1.w, c[7]);
}

__global__ __launch_bounds__(256) void compose_q(const float* __restrict__ U,
                                                 bf16_t* __restrict__ Qh,
                                                 bf16_t* __restrict__ Ql) {
  const int lane = threadIdx.x & 63;
  const int wave = threadIdx.x >> 6;
  const int col = blockIdx.x * 4 + wave;  // 0..511
  const int base = lane * 8;

  float c[8];
#pragma unroll
  for (int r = 0; r < 8; ++r) c[r] = (base + r == col) ? 1.0f : 0.0f;

  // software pipeline: rows k and k-1 resident, rows k-2/k-3 prefetching
  float4 a0, a1, b0, b1;
  {
    const float4* up = reinterpret_cast<const float4*>(U + (size_t)511 * D + base);
    a0 = up[0]; a1 = up[1];
    const float4* uq = reinterpret_cast<const float4*>(U + (size_t)510 * D + base);
    b0 = uq[0]; b1 = uq[1];
  }
  for (int k = 511; k >= 1; k -= 2) {
    float4 n0, n1, n2, n3;
    const bool has2 = (k >= 3);
    if (has2) {
      const float4* up = reinterpret_cast<const float4*>(U + (size_t)(k - 2) * D + base);
      n0 = up[0]; n1 = up[1];
      const float4* uq = reinterpret_cast<const float4*>(U + (size_t)(k - 3) * D + base);
      n2 = uq[0]; n3 = uq[1];
    }
    hh_step(c, a0, a1);  // row k
    hh_step(c, b0, b1);  // row k-1
    if (has2) { a0 = n0; a1 = n1; b0 = n2; b1 = n3; }
  }

#pragma unroll
  for (int r = 0; r < 8; ++r) {
    float q = c[r];
    bf16_t hi = (bf16_t)q;
    float lo = q - (float)hi;
    Qh[(size_t)(base + r) * D + col] = hi;
    Ql[(size_t)(base + r) * D + col] = (bf16_t)lo;
  }
}

// ---------------- Phase 2: out = X @ Q^T ----------------
#define BM 128
#define BN 128
#define BK 32
#define LSTR 40  // bf16 elems; 80B rows -> worst 2-way bank aliasing (free)
#define NKT (D / BK)

__global__ __launch_bounds__(256, 2) void gemm_xqt(const float* __restrict__ X,
                                                   const bf16_t* __restrict__ Qh,
                                                   const bf16_t* __restrict__ Ql,
                                                   float* __restrict__ out) {
  __shared__ __align__(16) bf16_t Ah[2][BM * LSTR];
  __shared__ __align__(16) bf16_t Al[2][BM * LSTR];
  __shared__ __align__(16) bf16_t Bh[2][BN * LSTR];
  __shared__ __align__(16) bf16_t Bl[2][BN * LSTR];

  const int tid = threadIdx.x;
  const int lane = tid & 63;
  const int wave = tid >> 6;

  // XCD-aware swizzle: 2048 blocks, %8==0 -> simple bijective remap.
  // Each XCD gets 256 consecutive logical tiles = 64 M-tiles x all 4 N-tiles
  // (X-tile shared by the 4 N-blocks stays in that XCD's L2).
  const int nwg = (BATCHN / BM) * (D / BN);  // 2048
  const int lt = ((int)blockIdx.x & 7) * (nwg >> 3) + ((int)blockIdx.x >> 3);
  const int brow = (lt >> 2) * BM;
  const int bcol = (lt & 3) * BN;

  const int wr = wave >> 1;  // M half
  const int wc = wave & 1;   // N half

  const f32x4 zero = {0.f, 0.f, 0.f, 0.f};
  f32x4 acc[4][4];
#pragma unroll
  for (int m = 0; m < 4; ++m)
#pragma unroll
    for (int n = 0; n < 4; ++n) acc[m][n] = zero;

  // A staging: fully coalesced -- 8 lanes cover one 128B row of the K-slab
  const int ar = tid >> 3;        // 0..31
  const int ac = (tid & 7) * 4;   // f32 col 0..28
  // B staging: 4 lanes cover one 64B row
  const int b_r = tid >> 2;       // 0..63
  const int b_c = (tid & 3) * 8;  // bf16 col 0,8,16,24

  const int fr = lane & 15;
  const int fk = (lane >> 4) * 8;

  float4 af[4];
  uint4 bh0, bh1, bl0, bl1;

  // ---- prologue: tile 0 -> regs -> LDS[0] ----
#pragma unroll
  for (int j = 0; j < 4; ++j)
    af[j] = *reinterpret_cast<const float4*>(X + (size_t)(brow + ar + 32 * j) * D + ac);
  bh0 = *reinterpret_cast<const uint4*>(Qh + (size_t)(bcol + b_r) * D + b_c);
  bh1 = *reinterpret_cast<const uint4*>(Qh + (size_t)(bcol + 64 + b_r) * D + b_c);
  bl0 = *reinterpret_cast<const uint4*>(Ql + (size_t)(bcol + b_r) * D + b_c);
  bl1 = *reinterpret_cast<const uint4*>(Ql + (size_t)(bcol + 64 + b_r) * D + b_c);

#pragma unroll
  for (int j = 0; j < 4; ++j) {
    float vals[4] = {af[j].x, af[j].y, af[j].z, af[j].w};
    bf16x4 hv, lv;
#pragma unroll
    for (int e = 0; e < 4; ++e) {
      bf16_t h = (bf16_t)vals[e];
      hv[e] = h;
      lv[e] = (bf16_t)(vals[e] - (float)h);
    }
    const int idx = (ar + 32 * j) * LSTR + ac;
    *reinterpret_cast<bf16x4*>(&Ah[0][idx]) = hv;
    *reinterpret_cast<bf16x4*>(&Al[0][idx]) = lv;
  }
  *reinterpret_cast<uint4*>(&Bh[0][b_r * LSTR + b_c]) = bh0;
  *reinterpret_cast<uint4*>(&Bh[0][(b_r + 64) * LSTR + b_c]) = bh1;
  *reinterpret_cast<uint4*>(&Bl[0][b_r * LSTR + b_c]) = bl0;
  *reinterpret_cast<uint4*>(&Bl[0][(b_r + 64) * LSTR + b_c]) = bl1;

  for (int t = 0; t < NKT; ++t) {
    const int cur = t & 1;
    const int k1 = (t + 1) * BK;

    // ---- issue next tile's global loads (stay in flight across barrier) ----
    if (t + 1 < NKT) {
#pragma unroll
      for (int j = 0; j < 4; ++j)
        af[j] = *reinterpret_cast<const float4*>(X + (size_t)(brow + ar + 32 * j) * D + k1 + ac);
      bh0 = *reinterpret_cast<const uint4*>(Qh + (size_t)(bcol + b_r) * D + k1 + b_c);
      bh1 = *reinterpret_cast<const uint4*>(Qh + (size_t)(bcol + 64 + b_r) * D + k1 + b_c);
      bl0 = *reinterpret_cast<const uint4*>(Ql + (size_t)(bcol + b_r) * D + k1 + b_c);
      bl1 = *reinterpret_cast<const uint4*>(Ql + (size_t)(bcol + 64 + b_r) * D + k1 + b_c);
    }

    // T4 barrier: drain LDS only; vmcnt (the prefetch) survives the barrier.
    asm volatile("s_waitcnt lgkmcnt(0)" ::: "memory");
    __builtin_amdgcn_s_barrier();

    // ---- fragments + MFMA on LDS[cur] ----
    bf16x8 a_h[4], a_l[4], b_h[4], b_l[4];
#pragma unroll
    for (int m = 0; m < 4; ++m) {
      const int row = wr * 64 + m * 16 + fr;
      a_h[m] = *reinterpret_cast<const bf16x8*>(&Ah[cur][row * LSTR + fk]);
      a_l[m] = *reinterpret_cast<const bf16x8*>(&Al[cur][row * LSTR + fk]);
    }
#pragma unroll
    for (int n = 0; n < 4; ++n) {
      const int colr = wc * 64 + n * 16 + fr;
      b_h[n] = *reinterpret_cast<const bf16x8*>(&Bh[cur][colr * LSTR + fk]);
      b_l[n] = *reinterpret_cast<const bf16x8*>(&Bl[cur][colr * LSTR + fk]);
    }
#pragma unroll
    for (int m = 0; m < 4; ++m)
#pragma unroll
      for (int n = 0; n < 4; ++n) {
        acc[m][n] = __builtin_amdgcn_mfma_f32_16x16x32_bf16(a_h[m], b_h[n], acc[m][n], 0, 0, 0);
        acc[m][n] = __builtin_amdgcn_mfma_f32_16x16x32_bf16(a_h[m], b_l[n], acc[m][n], 0, 0, 0);
        acc[m][n] = __builtin_amdgcn_mfma_f32_16x16x32_bf16(a_l[m], b_h[n], acc[m][n], 0, 0, 0);
      }

    // ---- split + write next tile into the other buffer ----
    if (t + 1 < NKT) {
      const int nxt = cur ^ 1;
#pragma unroll
      for (int j = 0; j < 4; ++j) {
        float vals[4] = {af[j].x, af[j].y, af[j].z, af[j].w};
        bf16x4 hv, lv;
#pragma unroll
        for (int e = 0; e < 4; ++e) {
          bf16_t h = (bf16_t)vals[e];
          hv[e] = h;
          lv[e] = (bf16_t)(vals[e] - (float)h);
        }
        const int idx = (ar + 32 * j) * LSTR + ac;
        *reinterpret_cast<bf16x4*>(&Ah[nxt][idx]) = hv;
        *reinterpret_cast<bf16x4*>(&Al[nxt][idx]) = lv;
      }
      *reinterpret_cast<uint4*>(&Bh[nxt][b_r * LSTR + b_c]) = bh0;
      *reinterpret_cast<uint4*>(&Bh[nxt][(b_r + 64) * LSTR + b_c]) = bh1;
      *reinterpret_cast<uint4*>(&Bl[nxt][b_r * LSTR + b_c]) = bl0;
      *reinterpret_cast<uint4*>(&Bl[nxt][(b_r + 64) * LSTR + b_c]) = bl1;
    }
  }

  // ---- epilogue: C/D layout col=lane&15, row=(lane>>4)*4+j ----
  const int orow0 = brow + wr * 64;
  const int ocol0 = bcol + wc * 64;
  const int cr = (lane >> 4) * 4;
  const int cc = lane & 15;
#pragma unroll
  for (int m = 0; m < 4; ++m)
#pragma unroll
    for (int n = 0; n < 4; ++n)
#pragma unroll
      for (int j = 0; j < 4; ++j) {
        const int row = orow0 + m * 16 + cr + j;
        const int col = ocol0 + n * 16 + cc;
        out[(size_t)row * D + col] = acc[m][n][j];
      }
}

extern "C" void kernel_launch(void* const* d_in, const int* in_sizes, int n_in,
                              void* d_out, int out_size, void* d_ws, size_t ws_size,
                              hipStream_t stream) {
  const float* X = (const float*)d_in[0];
  const float* U = (const float*)d_in[1];
  float* out = (float*)d_out;

  bf16_t* Qh = (bf16_t*)d_ws;
  bf16_t* Ql = Qh + (size_t)D * D;  // 512 KiB each

  compose_q<<<D / 4, 256, 0, stream>>>(U, Qh, Ql);
  gemm_xqt<<<(BATCHN / BM) * (D / BN), 256, 0, stream>>>(X, Qh, Ql, out);
}

// Round 5
// 372.187 us; speedup vs baseline: 1.4329x; 1.3606x over previous
//
#include <hip/hip_runtime.h>
#include <hip/hip_bf16.h>

// Orthogonal: out = X @ Q^T with Q = prod_{i=0..511} (I - 2 u_i u_i^T).
// Phase 0: gram_k — pairwise dots g_ij = u_i.u_j within each group of 8
//          consecutive reflectors (application order), fully parallel.
// Phase 1: compose_q — blocked-reflector (compact-WY) application to columns
//          of I: per group of 8, the 8 raw dots reduce concurrently (DPP),
//          tiny scalar correction chain, one fused rank-8 update.
// Phase 2: gemm out = X Q^T, bf16 hi/lo split (3 MFMA terms, fp32 acc),
//          single-buffered LDS, 4 blocks/CU, T14 load-early/write-late.

#define D 512
#define BATCHN 65536

typedef __bf16 bf16_t;
typedef __bf16 bf16x4 __attribute__((ext_vector_type(4)));
typedef __bf16 bf16x8 __attribute__((ext_vector_type(8)));
typedef float f32x4 __attribute__((ext_vector_type(4)));

template <int CTRL, int ROWMASK>
__device__ __forceinline__ float dpp_add(float x) {
  int p = __builtin_amdgcn_update_dpp(0, __float_as_int(x), CTRL, ROWMASK, 0xf, true);
  return x + __int_as_float(p);
}

// Full-wave (64) sum; result broadcast to all lanes via readlane(63).
__device__ __forceinline__ float wave_sum64(float x) {
  x = dpp_add<0x111, 0xf>(x);  // row_shr:1
  x = dpp_add<0x112, 0xf>(x);  // row_shr:2
  x = dpp_add<0x114, 0xf>(x);  // row_shr:4
  x = dpp_add<0x118, 0xf>(x);  // row_shr:8
  x = dpp_add<0x142, 0xa>(x);  // row_bcast15
  x = dpp_add<0x143, 0xc>(x);  // row_bcast31 -> lane63 has total
  return __int_as_float(__builtin_amdgcn_readlane(__float_as_int(x), 63));
}

// ---------------- Phase 0: Gram ----------------
// One wave per (group g, pair p=(i,j), j<i). Rows: 511-8g-i, 511-8g-j.
__global__ __launch_bounds__(64) void gram_k(const float* __restrict__ U,
                                             float* __restrict__ G) {
  const int lane = threadIdx.x;
  const int g = blockIdx.x / 28;
  const int p0 = blockIdx.x % 28;
  int p = p0, i = 1, t = 0;
  while (p >= t + i) { t += i; ++i; }
  const int j = p - t;
  const int ra = 511 - 8 * g - i;
  const int rb = 511 - 8 * g - j;
  const int base = lane * 8;
  const float4* pa = reinterpret_cast<const float4*>(U + (size_t)ra * D + base);
  const float4* pb = reinterpret_cast<const float4*>(U + (size_t)rb * D + base);
  float4 a0 = pa[0], a1 = pa[1], b0 = pb[0], b1 = pb[1];
  float m0 = a0.x * b0.x + a0.y * b0.y, m1 = a0.z * b0.z + a0.w * b0.w;
  float m2 = a1.x * b1.x + a1.y * b1.y, m3 = a1.z * b1.z + a1.w * b1.w;
  float tot = wave_sum64((m0 + m1) + (m2 + m3));
  if (lane == 0) G[g * 32 + p0] = tot;
}

// ---------------- Phase 1: compose Q ----------------
// One wave per column (512 blocks x 64 threads).
__global__ __launch_bounds__(64) void compose_q(const float* __restrict__ U,
                                                const float* __restrict__ G,
                                                bf16_t* __restrict__ Qh,
                                                bf16_t* __restrict__ Ql) {
  const int lane = threadIdx.x;
  const int col = blockIdx.x;
  const int base = lane * 8;

  float x[8];
#pragma unroll
  for (int e = 0; e < 8; ++e) x[e] = (base + e == col) ? 1.0f : 0.0f;

  float4 cA[8], cB[8], nA[8], nB[8];
  float gcf[32], gnf[32];

#pragma unroll
  for (int i = 0; i < 8; ++i) {
    const float* rp = U + (size_t)(511 - i) * D + base;
    cA[i] = *reinterpret_cast<const float4*>(rp);
    cB[i] = *reinterpret_cast<const float4*>(rp + 4);
  }
#pragma unroll
  for (int q = 0; q < 8; ++q)
    *reinterpret_cast<float4*>(&gcf[q * 4]) = *reinterpret_cast<const float4*>(G + q * 4);

  for (int g = 0; g < 64; ++g) {
    if (g < 63) {
#pragma unroll
      for (int i = 0; i < 8; ++i) {
        const float* rp = U + (size_t)(511 - 8 * (g + 1) - i) * D + base;
        nA[i] = *reinterpret_cast<const float4*>(rp);
        nB[i] = *reinterpret_cast<const float4*>(rp + 4);
      }
#pragma unroll
      for (int q = 0; q < 8; ++q)
        *reinterpret_cast<float4*>(&gnf[q * 4]) =
            *reinterpret_cast<const float4*>(G + (g + 1) * 32 + q * 4);
    }

    // 8 raw dots r_i = u_i . x  (independent DPP reduce chains -> ILP)
    float r[8];
#pragma unroll
    for (int i = 0; i < 8; ++i) {
      float m0 = cA[i].x * x[0] + cA[i].y * x[1];
      float m1 = cA[i].z * x[2] + cA[i].w * x[3];
      float m2 = cB[i].x * x[4] + cB[i].y * x[5];
      float m3 = cB[i].z * x[6] + cB[i].w * x[7];
      r[i] = wave_sum64((m0 + m1) + (m2 + m3));
    }

    // corrections: d_i = r_i - 2 sum_{j<i} g_ij d_j
    float d0 = r[0];
    float d1 = r[1] - 2.f * (gcf[0] * d0);
    float d2 = r[2] - 2.f * (gcf[1] * d0 + gcf[2] * d1);
    float d3 = r[3] - 2.f * (gcf[3] * d0 + gcf[4] * d1 + gcf[5] * d2);
    float d4 = r[4] - 2.f * (gcf[6] * d0 + gcf[7] * d1 + gcf[8] * d2 + gcf[9] * d3);
    float d5 = r[5] - 2.f * (gcf[10] * d0 + gcf[11] * d1 + gcf[12] * d2 + gcf[13] * d3 +
                             gcf[14] * d4);
    float d6 = r[6] - 2.f * (gcf[15] * d0 + gcf[16] * d1 + gcf[17] * d2 + gcf[18] * d3 +
                             gcf[19] * d4 + gcf[20] * d5);
    float d7 = r[7] - 2.f * (gcf[21] * d0 + gcf[22] * d1 + gcf[23] * d2 + gcf[24] * d3 +
                             gcf[25] * d4 + gcf[26] * d5 + gcf[27] * d6);

    const float s[8] = {2.f * d0, 2.f * d1, 2.f * d2, 2.f * d3,
                        2.f * d4, 2.f * d5, 2.f * d6, 2.f * d7};
    // fused rank-8 update: x -= sum_i s_i u_i
#pragma unroll
    for (int i = 0; i < 8; ++i) {
      x[0] = fmaf(-s[i], cA[i].x, x[0]);
      x[1] = fmaf(-s[i], cA[i].y, x[1]);
      x[2] = fmaf(-s[i], cA[i].z, x[2]);
      x[3] = fmaf(-s[i], cA[i].w, x[3]);
      x[4] = fmaf(-s[i], cB[i].x, x[4]);
      x[5] = fmaf(-s[i], cB[i].y, x[5]);
      x[6] = fmaf(-s[i], cB[i].z, x[6]);
      x[7] = fmaf(-s[i], cB[i].w, x[7]);
    }

    if (g < 63) {
#pragma unroll
      for (int i = 0; i < 8; ++i) { cA[i] = nA[i]; cB[i] = nB[i]; }
#pragma unroll
      for (int q = 0; q < 32; ++q) gcf[q] = gnf[q];
    }
  }

#pragma unroll
  for (int e = 0; e < 8; ++e) {
    float q = x[e];
    bf16_t hi = (bf16_t)q;
    float lo = q - (float)hi;
    Qh[(size_t)(base + e) * D + col] = hi;
    Ql[(size_t)(base + e) * D + col] = (bf16_t)lo;
  }
}

// ---------------- Phase 2: out = X @ Q^T ----------------
#define BM 128
#define BN 64
#define BK 32
#define LSTR 40  // bf16 elems; measured 0 bank conflicts with this stride
#define NKT (D / BK)

__global__ __launch_bounds__(256, 4) void gemm_xqt(const float* __restrict__ X,
                                                   const bf16_t* __restrict__ Qh,
                                                   const bf16_t* __restrict__ Ql,
                                                   float* __restrict__ out) {
  __shared__ __align__(16) bf16_t Ah[BM * LSTR];
  __shared__ __align__(16) bf16_t Al[BM * LSTR];
  __shared__ __align__(16) bf16_t Bh[BN * LSTR];
  __shared__ __align__(16) bf16_t Bl[BN * LSTR];

  const int tid = threadIdx.x;
  const int lane = tid & 63;
  const int wave = tid >> 6;

  // XCD swizzle (4096 blocks, %8==0): consecutive lt on same XCD; the 8
  // N-tiles of one M-row are consecutive -> X slab L2-resident per XCD.
  const int nwg = (BATCHN / BM) * (D / BN);  // 4096
  const int lt = ((int)blockIdx.x & 7) * (nwg >> 3) + ((int)blockIdx.x >> 3);
  const int brow = (lt >> 3) * BM;
  const int bcol = (lt & 7) * BN;

  const int wr = wave >> 1;  // 0..1: M 64-half
  const int wc = wave & 1;   // 0..1: N 32-half

  const f32x4 zero = {0.f, 0.f, 0.f, 0.f};
  f32x4 acc[4][2];
#pragma unroll
  for (int m = 0; m < 4; ++m)
#pragma unroll
    for (int n = 0; n < 2; ++n) acc[m][n] = zero;

  // A staging: 8 lanes per 128B row-slab; 4 row-blocks of 32
  const int ar = tid >> 3;        // 0..31
  const int ac = (tid & 7) * 4;   // f32 col
  // B staging: 4 lanes per 64B row; 64 rows x 32 bf16
  const int b_r = tid >> 2;       // 0..63
  const int b_c = (tid & 3) * 8;  // bf16 col

  const int fr = lane & 15;
  const int fk = (lane >> 4) * 8;

  float4 af[4];
  uint4 bh, bl;

  // prologue: issue tile-0 loads
#pragma unroll
  for (int j = 0; j < 4; ++j)
    af[j] = *reinterpret_cast<const float4*>(X + (size_t)(brow + ar + 32 * j) * D + ac);
  bh = *reinterpret_cast<const uint4*>(Qh + (size_t)(bcol + b_r) * D + b_c);
  bl = *reinterpret_cast<const uint4*>(Ql + (size_t)(bcol + b_r) * D + b_c);

  for (int t = 0; t < NKT; ++t) {
    if (t > 0) {
      asm volatile("s_waitcnt lgkmcnt(0)" ::: "memory");
      __builtin_amdgcn_s_barrier();  // all waves done reading previous tile
    }

    // write tile t (compiler inserts vmcnt waits on af/bh/bl)
#pragma unroll
    for (int j = 0; j < 4; ++j) {
      float vals[4] = {af[j].x, af[j].y, af[j].z, af[j].w};
      bf16x4 hv, lv;
#pragma unroll
      for (int e = 0; e < 4; ++e) {
        bf16_t h = (bf16_t)vals[e];
        hv[e] = h;
        lv[e] = (bf16_t)(vals[e] - (float)h);
      }
      const int idx = (ar + 32 * j) * LSTR + ac;
      *reinterpret_cast<bf16x4*>(&Ah[idx]) = hv;
      *reinterpret_cast<bf16x4*>(&Al[idx]) = lv;
    }
    *reinterpret_cast<uint4*>(&Bh[b_r * LSTR + b_c]) = bh;
    *reinterpret_cast<uint4*>(&Bl[b_r * LSTR + b_c]) = bl;

    asm volatile("s_waitcnt lgkmcnt(0)" ::: "memory");
    __builtin_amdgcn_s_barrier();  // tile t visible

    // T14: issue next tile's loads now; they fly under ds_read + MFMA
    if (t + 1 < NKT) {
      const int k1 = (t + 1) * BK;
#pragma unroll
      for (int j = 0; j < 4; ++j)
        af[j] = *reinterpret_cast<const float4*>(X + (size_t)(brow + ar + 32 * j) * D + k1 + ac);
      bh = *reinterpret_cast<const uint4*>(Qh + (size_t)(bcol + b_r) * D + k1 + b_c);
      bl = *reinterpret_cast<const uint4*>(Ql + (size_t)(bcol + b_r) * D + k1 + b_c);
    }

    bf16x8 b_h[2], b_l[2];
#pragma unroll
    for (int n = 0; n < 2; ++n) {
      const int colr = wc * 32 + n * 16 + fr;
      b_h[n] = *reinterpret_cast<const bf16x8*>(&Bh[colr * LSTR + fk]);
      b_l[n] = *reinterpret_cast<const bf16x8*>(&Bl[colr * LSTR + fk]);
    }
    __builtin_amdgcn_s_setprio(1);
#pragma unroll
    for (int m = 0; m < 4; ++m) {
      const int row = wr * 64 + m * 16 + fr;
      bf16x8 a_h = *reinterpret_cast<const bf16x8*>(&Ah[row * LSTR + fk]);
      bf16x8 a_l = *reinterpret_cast<const bf16x8*>(&Al[row * LSTR + fk]);
#pragma unroll
      for (int n = 0; n < 2; ++n) {
        acc[m][n] = __builtin_amdgcn_mfma_f32_16x16x32_bf16(a_h, b_h[n], acc[m][n], 0, 0, 0);
        acc[m][n] = __builtin_amdgcn_mfma_f32_16x16x32_bf16(a_h, b_l[n], acc[m][n], 0, 0, 0);
        acc[m][n] = __builtin_amdgcn_mfma_f32_16x16x32_bf16(a_l, b_h[n], acc[m][n], 0, 0, 0);
      }
    }
    __builtin_amdgcn_s_setprio(0);
  }

  // epilogue: C/D layout col=lane&15, row=(lane>>4)*4+j
  const int orow0 = brow + wr * 64;
  const int ocol0 = bcol + wc * 32;
  const int cr = (lane >> 4) * 4;
  const int cc = lane & 15;
#pragma unroll
  for (int m = 0; m < 4; ++m)
#pragma unroll
    for (int n = 0; n < 2; ++n)
#pragma unroll
      for (int j = 0; j < 4; ++j) {
        const int row = orow0 + m * 16 + cr + j;
        const int col = ocol0 + n * 16 + cc;
        out[(size_t)row * D + col] = acc[m][n][j];
      }
}

extern "C" void kernel_launch(void* const* d_in, const int* in_sizes, int n_in,
                              void* d_out, int out_size, void* d_ws, size_t ws_size,
                              hipStream_t stream) {
  const float* X = (const float*)d_in[0];
  const float* U = (const float*)d_in[1];
  float* out = (float*)d_out;

  bf16_t* Qh = (bf16_t*)d_ws;                      // 512 KiB
  bf16_t* Ql = Qh + (size_t)D * D;                 // 512 KiB
  float* G = (float*)((char*)d_ws + 2 * (size_t)D * D * sizeof(bf16_t));  // 8 KiB

  gram_k<<<64 * 28, 64, 0, stream>>>(U, G);
  compose_q<<<D, 64, 0, stream>>>(U, G, Qh, Ql);
  gemm_xqt<<<(BATCHN / BM) * (D / BN), 256, 0, stream>>>(X, Qh, Ql, out);
}